// Round 6
// baseline (507.510 us; speedup 1.0000x reference)
//
#include <hip/hip_runtime.h>
#include <hip/hip_bf16.h>

#define EPS_F 1e-10f

typedef short s16x8 __attribute__((ext_vector_type(8)));
typedef float f32x4 __attribute__((ext_vector_type(4)));
typedef unsigned short ushort_t;

constexpr int B_ = 8, S_ = 4, C_ = 512, Cq_ = 128, HW_ = 4096;
constexpr long long D_ = (long long)Cq_ * HW_;

__device__ inline float bf_lo(unsigned int u) { return __uint_as_float(u << 16); }
__device__ inline float bf_hi(unsigned int u) { return __uint_as_float(u & 0xffff0000u); }

__device__ inline ushort_t f2bf(float f) {
    __hip_bfloat16 h = __float2bfloat16(f);
    return *reinterpret_cast<ushort_t*>(&h);
}
__device__ inline unsigned int pack_bf2(float a, float b) {
    return (unsigned int)f2bf(a) | ((unsigned int)f2bf(b) << 16);
}
__device__ inline float dot8(uint4 a, uint4 b) {
    return bf_lo(a.x) * bf_lo(b.x) + bf_hi(a.x) * bf_hi(b.x)
         + bf_lo(a.y) * bf_lo(b.y) + bf_hi(a.y) * bf_hi(b.y)
         + bf_lo(a.z) * bf_lo(b.z) + bf_hi(a.z) * bf_hi(b.z)
         + bf_lo(a.w) * bf_lo(b.w) + bf_hi(a.w) * bf_hi(b.w);
}

#define GLOAD16(gp, lp) __builtin_amdgcn_global_load_lds( \
    (const __attribute__((address_space(1))) unsigned int*)(gp), \
    (__attribute__((address_space(3))) unsigned int*)(lp), 16, 0, 0)

#define VMCNT0 asm volatile("s_waitcnt vmcnt(0)" ::: "memory")
#define LGK0   asm volatile("s_waitcnt lgkmcnt(0)" ::: "memory")
#define MFMA16(a, b, c) __builtin_amdgcn_mfma_f32_16x16x32_bf16(a, b, c, 0, 0, 0)

// swizzle involution (8 16B-chunk slots per 64-elem row), p in [0,64)
#define SWZ(p) ((((p) >> 3) & 7) ^ ((p) & 7))

// ---------------------------------------------------------------------------
// prep3: fp32->bf16 weights, pre-swizzled (chunk slot = c ^ (row&7)) so
// global_load_lds (linear dest) + swizzled ds_read_b128 is conflict-free.
// Also zeroes g4.
// ---------------------------------------------------------------------------
__global__ __launch_bounds__(256) void prep3(
    const float* __restrict__ wq, const float* __restrict__ wk,
    const float* __restrict__ wv,
    ushort_t* __restrict__ Wqk_pre, ushort_t* __restrict__ Wvb_pre,
    float* __restrict__ g4) {
    int gid = blockIdx.x * 256 + threadIdx.x;
    if (gid < 8 * 24 * 16) g4[gid] = 0.f;
    if (gid < 65536) {                      // Wqk chunks
        int s = gid >> 14;
        int kt = (gid >> 11) & 7;
        int row = (gid >> 3) & 255;
        int slot = gid & 7;
        int col = kt * 64 + ((slot ^ (row & 7)) << 3);
        const float* src = (row < 128)
            ? &wq[((size_t)s * 128 + row) * 512 + col]
            : &wk[((size_t)s * 128 + (row - 128)) * 512 + col];
        float4 f0 = *reinterpret_cast<const float4*>(src);
        float4 f1 = *reinterpret_cast<const float4*>(src + 4);
        uint4 o;
        o.x = pack_bf2(f0.x, f0.y); o.y = pack_bf2(f0.z, f0.w);
        o.z = pack_bf2(f1.x, f1.y); o.w = pack_bf2(f1.z, f1.w);
        *reinterpret_cast<uint4*>(Wqk_pre + (size_t)gid * 8) = o;
    } else {                                 // Wvb chunks
        int c2 = gid - 65536;                // < 131072
        int t = c2 >> 15;
        int ct = (c2 >> 14) & 1;
        int kt = (c2 >> 11) & 7;
        int row = (c2 >> 3) & 255;
        int slot = c2 & 7;
        int col = kt * 64 + ((slot ^ (row & 7)) << 3);
        const float* src = &wv[((size_t)t * 512 + ct * 256 + row) * 512 + col];
        float4 f0 = *reinterpret_cast<const float4*>(src);
        float4 f1 = *reinterpret_cast<const float4*>(src + 4);
        uint4 o;
        o.x = pack_bf2(f0.x, f0.y); o.y = pack_bf2(f0.z, f0.w);
        o.z = pack_bf2(f1.x, f1.y); o.w = pack_bf2(f1.z, f1.w);
        *reinterpret_cast<uint4*>(Wvb_pre + (size_t)c2 * 8) = o;
    }
}

// ---------------------------------------------------------------------------
// Common tile geometry (r6): BM=256 (c), BN=32 (p), BK=64, 512 thr = 8 waves
// (4 wr x 2 wc), wave tile 64c x 16p, 8 MFMA/wave/step, 2-buffer LDS drain
// pipeline (m97 model), 2 blocks/CU (LDS 72KB, regs <=128 via launch_bounds).
// A LDS: [256 rows][slot 8][8 bf16], slot = (k>>3) ^ (row&7)  (linear gload).
// B LDS: [32 p][slot 8][8 bf16],     slot = (k>>3) ^ SWZ(p).
// ---------------------------------------------------------------------------

// A frag read offset (ushort): row r at chunk (h*4+lk)^(r&7)
#define DECLS_COMMON()                                                       \
    const int tid = threadIdx.x;                                             \
    const int w = tid >> 6, lane = tid & 63;                                 \
    const int w4 = w * 4;                                                    \
    const int wr = w >> 1, wc = w & 1;                                       \
    const int li = lane & 15, lk = lane >> 4;                                \
    const int arow = wr * 64;                                                \
    const int bp = wc * 16 + li;                                             \
    int a_sl[2], b_sl[2];                                                    \
    _Pragma("unroll")                                                        \
    for (int h = 0; h < 2; ++h) {                                            \
        a_sl[h] = (((h * 4 + lk) ^ (li & 7)) << 3);                          \
        b_sl[h] = (((h * 4 + lk) ^ SWZ(bp)) << 3);                           \
    }

// ===========================================================================
// qk6: [Wq;Wk](256x512) @ X[b,t](512x4096) + bias -> Qb, Kb; also emits
// transposed bf16 x (xbfT[bt][p][c], chunk-swizzled) for vblend6.
// ===========================================================================
__global__ __launch_bounds__(512, 4) void qk6(
    const ushort_t* __restrict__ Wqk_pre, const float* __restrict__ x,
    const float* __restrict__ bq, const float* __restrict__ bk,
    ushort_t* __restrict__ Qb, ushort_t* __restrict__ Kb,
    ushort_t* __restrict__ xbfT) {

    // 4096 blocks; XCD-contiguous: xcd handles bt in [xcd*4, xcd*4+4)
    const int xcd = blockIdx.x & 7;
    const int idx = blockIdx.x >> 3;          // 0..511
    const int bt = xcd * 4 + (idx >> 7);
    const int s = bt & 3;
    const int p0 = (idx & 127) * 32;

    __shared__ __align__(16) ushort_t AsAll[2 * 16384];  // 64KB
    __shared__ __align__(16) ushort_t BsAll[2 * 2048];   // 8KB

    DECLS_COMMON();

    // B staging: thread -> k=tid>>3 (0..63), p-base=(tid&7)*4
    const int sk = tid >> 3, spb = (tid & 7) * 4;
    // emission (threads 0..255): LDS chunk (p=tid>>3, slot=tid&7)
    const int ep = tid >> 3, esl = tid & 7;
    const int ec = esl ^ SWZ(ep);

    const float* Bx = x + (size_t)bt * C_ * HW_ + p0 + spb;

    f32x4 acc[4];
#pragma unroll
    for (int mf = 0; mf < 4; ++mf) acc[mf] = 0.f;

    float4 nb;

#define STAGE_A6(T, BUF)                                                     \
    { const ushort_t* _tp = Wqk_pre + ((size_t)(s * 8 + (T)) << 14);         \
      ushort_t* _ld = &AsAll[(BUF) * 16384];                                 \
      _Pragma("unroll")                                                      \
      for (int _i = 0; _i < 4; ++_i)                                         \
          GLOAD16(_tp + ((w4 + _i) << 9) + (lane << 3),                      \
                  _ld + ((w4 + _i) << 9)); }

#define LOAD_B6(T) nb = *reinterpret_cast<const float4*>(Bx + (size_t)((T) * 64 + sk) * HW_)

#define WRITE_B6(BUF)                                                        \
    { float _vv[4] = {nb.x, nb.y, nb.z, nb.w};                               \
      _Pragma("unroll")                                                      \
      for (int _j = 0; _j < 4; ++_j) {                                       \
          int _p = spb + _j;                                                 \
          BsAll[(BUF) * 2048 + _p * 64 + (((sk >> 3) ^ SWZ(_p)) << 3)        \
                + (sk & 7)] = f2bf(_vv[_j]);                                 \
      } }

#define EMIT6(T, BUF)                                                        \
    if (w < 4) {                                                             \
        s16x8 _ev = *reinterpret_cast<const s16x8*>(&BsAll[(BUF) * 2048 + tid * 8]); \
        *reinterpret_cast<s16x8*>(                                           \
            xbfT + ((size_t)bt * HW_ + p0 + ep) * 512 + (T) * 64 + ec * 8) = _ev; \
    }

#define COMPUTE6Q(BUF)                                                       \
    { const int _ab = (BUF) * 16384, _bb = (BUF) * 2048;                     \
      _Pragma("unroll")                                                      \
      for (int h = 0; h < 2; ++h) {                                          \
          s16x8 af0 = *reinterpret_cast<const s16x8*>(                       \
              &AsAll[_ab + (arow + 0 * 16 + li) * 64 + a_sl[h]]);            \
          s16x8 af1 = *reinterpret_cast<const s16x8*>(                       \
              &AsAll[_ab + (arow + 1 * 16 + li) * 64 + a_sl[h]]);            \
          s16x8 af2 = *reinterpret_cast<const s16x8*>(                       \
              &AsAll[_ab + (arow + 2 * 16 + li) * 64 + a_sl[h]]);            \
          s16x8 af3 = *reinterpret_cast<const s16x8*>(                       \
              &AsAll[_ab + (arow + 3 * 16 + li) * 64 + a_sl[h]]);            \
          s16x8 bf = *reinterpret_cast<const s16x8*>(                        \
              &BsAll[_bb + bp * 64 + b_sl[h]]);                              \
          __builtin_amdgcn_s_setprio(1);                                     \
          acc[0] = MFMA16(af0, bf, acc[0]);                                  \
          acc[1] = MFMA16(af1, bf, acc[1]);                                  \
          acc[2] = MFMA16(af2, bf, acc[2]);                                  \
          acc[3] = MFMA16(af3, bf, acc[3]);                                  \
          __builtin_amdgcn_s_setprio(0);                                     \
      } }

    // prologue
    LOAD_B6(0);
    STAGE_A6(0, 0);
    WRITE_B6(0);
    VMCNT0; LGK0;
    __builtin_amdgcn_s_barrier();

#pragma unroll
    for (int t = 0; t < 8; ++t) {
        if (t < 7) { LOAD_B6(t + 1); STAGE_A6(t + 1, (t + 1) & 1); }
        EMIT6(t, t & 1);               // store overlaps compute; drained next VMCNT0
        COMPUTE6Q(t & 1);
        if (t < 7) {
            WRITE_B6((t + 1) & 1);
            VMCNT0; LGK0;
            __builtin_amdgcn_s_barrier();
        }
    }

#undef STAGE_A6
#undef LOAD_B6
#undef WRITE_B6
#undef EMIT6
#undef COMPUTE6Q

    // epilogue: +bias, split Q/K (wave-uniform: wr<2 -> Q)
#pragma unroll
    for (int mf = 0; mf < 4; ++mf) {
#pragma unroll
        for (int r = 0; r < 4; ++r) {
            int m = wr * 64 + mf * 16 + lk * 4 + r;
            float bias = (m < 128) ? bq[s * 128 + m] : bk[s * 128 + (m - 128)];
            int p = p0 + wc * 16 + li;
            float vv = acc[mf][r] + bias;
            if (m < 128)
                Qb[(size_t)bt * D_ + (size_t)m * HW_ + p] = f2bf(vv);
            else
                Kb[(size_t)bt * D_ + (size_t)(m - 128) * HW_ + p] = f2bf(vv);
        }
    }
}

// ===========================================================================
// vblend6: fused V-GEMM + attention blend + bias + gamma + residual.
// Wave tile 64c x 16p -> mst[4][4]+acc[4] = 80 regs; launch_bounds(512,4)
// forces <=128 unified regs -> 4 waves/SIMD, 2 blocks/CU.
// ===========================================================================
__global__ __launch_bounds__(512, 4) void vblend6(
    const ushort_t* __restrict__ Wvb_pre, const ushort_t* __restrict__ xbfT,
    const float* __restrict__ x, const float* __restrict__ bv,
    const float* __restrict__ att, const float* __restrict__ gamma,
    float* __restrict__ out) {

    // 2048 blocks: b = XCD; r_ = 0..255 -> ct, p0
    const int b = blockIdx.x & 7;
    const int r_ = blockIdx.x >> 3;
    const int ct = r_ >> 7;
    const int p0 = (r_ & 127) * 32;

    __shared__ __align__(16) ushort_t AsAll[2 * 16384];  // 64KB
    __shared__ __align__(16) ushort_t BsAll[2 * 2048];   // 8KB

    DECLS_COMMON();

    // att weights in scalar regs (block-uniform; static-indexed only)
    float attv[16];
#pragma unroll
    for (int i = 0; i < 16; ++i)
        attv[i] = __uint_as_float(__builtin_amdgcn_readfirstlane(
            __float_as_uint(att[b * 16 + i])));

    // B staging source (threads 0..255): p=tid>>3 (0..31), slot=tid&7
    const int sp_ = tid >> 3;
    const int sc_ = (tid & 7) ^ SWZ(sp_);
    const ushort_t* bsrc = xbfT + ((size_t)b * 4 * HW_ + p0 + sp_) * 512 + sc_ * 8;

    f32x4 acc[4];
    f32x4 mst[4][4];   // [s][mf]
#pragma unroll
    for (int mf = 0; mf < 4; ++mf) acc[mf] = 0.f;
#pragma unroll
    for (int so = 0; so < 4; ++so)
#pragma unroll
        for (int mf = 0; mf < 4; ++mf) mst[so][mf] = 0.f;

#define STAGE6(T, BUF)                                                       \
    { const ushort_t* _ap = Wvb_pre +                                        \
          (((size_t)(((T) >> 3) * 2 + ct) * 8 + ((T) & 7)) << 14);           \
      ushort_t* _al = &AsAll[(BUF) * 16384];                                 \
      _Pragma("unroll")                                                      \
      for (int _i = 0; _i < 4; ++_i)                                         \
          GLOAD16(_ap + ((w4 + _i) << 9) + (lane << 3),                      \
                  _al + ((w4 + _i) << 9));                                   \
      if (w < 4)                                                             \
          GLOAD16(bsrc + (size_t)((T) >> 3) * HW_ * 512 + ((T) & 7) * 64,    \
                  &BsAll[(BUF) * 2048 + w * 512]); }

#define COMPUTE6(BUF)                                                        \
    { const int _ab = (BUF) * 16384, _bb = (BUF) * 2048;                     \
      _Pragma("unroll")                                                      \
      for (int h = 0; h < 2; ++h) {                                          \
          s16x8 af0 = *reinterpret_cast<const s16x8*>(                       \
              &AsAll[_ab + (arow + 0 * 16 + li) * 64 + a_sl[h]]);            \
          s16x8 af1 = *reinterpret_cast<const s16x8*>(                       \
              &AsAll[_ab + (arow + 1 * 16 + li) * 64 + a_sl[h]]);            \
          s16x8 af2 = *reinterpret_cast<const s16x8*>(                       \
              &AsAll[_ab + (arow + 2 * 16 + li) * 64 + a_sl[h]]);            \
          s16x8 af3 = *reinterpret_cast<const s16x8*>(                       \
              &AsAll[_ab + (arow + 3 * 16 + li) * 64 + a_sl[h]]);            \
          s16x8 bf = *reinterpret_cast<const s16x8*>(                        \
              &BsAll[_bb + bp * 64 + b_sl[h]]);                              \
          __builtin_amdgcn_s_setprio(1);                                     \
          acc[0] = MFMA16(af0, bf, acc[0]);                                  \
          acc[1] = MFMA16(af1, bf, acc[1]);                                  \
          acc[2] = MFMA16(af2, bf, acc[2]);                                  \
          acc[3] = MFMA16(af3, bf, acc[3]);                                  \
          __builtin_amdgcn_s_setprio(0);                                     \
      } }

#define BLEND6(T2)                                                           \
    { _Pragma("unroll")                                                      \
      for (int _so = 0; _so < 4; ++_so)                                      \
          _Pragma("unroll")                                                  \
          for (int _mf = 0; _mf < 4; ++_mf)                                  \
              mst[_so][_mf] += attv[_so * 4 + (T2)] * acc[_mf];              \
      _Pragma("unroll")                                                      \
      for (int _mf = 0; _mf < 4; ++_mf) acc[_mf] = 0.f; }

    // prologue
    STAGE6(0, 0);
    VMCNT0;
    __builtin_amdgcn_s_barrier();

#pragma unroll
    for (int t = 0; t < 32; ++t) {
        if (t < 31) STAGE6(t + 1, (t + 1) & 1);
        COMPUTE6(t & 1);
        if (t == 7)  BLEND6(0);
        if (t == 15) BLEND6(1);
        if (t == 23) BLEND6(2);
        if (t == 31) BLEND6(3);
        if (t < 31) {
            VMCNT0; LGK0;
            __builtin_amdgcn_s_barrier();
        }
    }

#undef STAGE6
#undef COMPUTE6
#undef BLEND6

    // epilogue: out = gm*(mst + sum_t att*bv) + x
    const float gm = gamma[0];
    const int c0 = ct * 256;
#pragma unroll
    for (int mf = 0; mf < 4; ++mf) {
#pragma unroll
        for (int r = 0; r < 4; ++r) {
            int c = c0 + wr * 64 + mf * 16 + lk * 4 + r;
            float bvv[4];
#pragma unroll
            for (int t = 0; t < 4; ++t) bvv[t] = bv[(size_t)t * 512 + c];
#pragma unroll
            for (int so = 0; so < 4; ++so) {
                float bsum = attv[so * 4 + 0] * bvv[0] + attv[so * 4 + 1] * bvv[1]
                           + attv[so * 4 + 2] * bvv[2] + attv[so * 4 + 3] * bvv[3];
                int p = p0 + wc * 16 + li;
                size_t off = ((size_t)(b * 4 + so) * C_ + c) * HW_ + p;
                out[off] = gm * (mst[so][mf][r] + bsum) + x[off];
            }
        }
    }
}

// ---------------------------------------------------------------------------
// gram5: all 24 reductions per (b, D/16-slice); Q/K read once. Deterministic.
// ---------------------------------------------------------------------------
__global__ __launch_bounds__(256) void gram5(
    const ushort_t* __restrict__ Q, const ushort_t* __restrict__ K,
    float* __restrict__ g4) {

    const int ch = blockIdx.x;       // 0..15
    const int b  = blockIdx.y;       // 0..7
    const size_t base = (size_t)ch * (D_ / 16);

    const uint4* qv[4];
    const uint4* kv[4];
#pragma unroll
    for (int s = 0; s < 4; ++s) {
        qv[s] = reinterpret_cast<const uint4*>(Q + (size_t)(b * 4 + s) * D_ + base);
        kv[s] = reinterpret_cast<const uint4*>(K + (size_t)(b * 4 + s) * D_ + base);
    }

    float accr[24];
#pragma unroll
    for (int e = 0; e < 24; ++e) accr[e] = 0.f;

    const int n8 = (int)(D_ / 16 / 8);
    for (int i = threadIdx.x; i < n8; i += 256) {
        uint4 qa[4], ka[4];
#pragma unroll
        for (int s = 0; s < 4; ++s) { qa[s] = qv[s][i]; ka[s] = kv[s][i]; }
#pragma unroll
        for (int s = 0; s < 4; ++s) {
#pragma unroll
            for (int u = 0; u < 4; ++u) accr[s * 4 + u] += dot8(qa[s], ka[u]);
            accr[16 + s] += dot8(qa[s], qa[s]);
            accr[20 + s] += dot8(ka[s], ka[s]);
        }
    }

    __shared__ float red[4][24];
    const int lane = threadIdx.x & 63, wid = threadIdx.x >> 6;
#pragma unroll
    for (int e = 0; e < 24; ++e) {
        float v = accr[e];
#pragma unroll
        for (int o = 32; o > 0; o >>= 1) v += __shfl_down(v, o);
        if (lane == 0) red[wid][e] = v;
    }
    __syncthreads();
    if (threadIdx.x < 24) {
        float t = red[0][threadIdx.x] + red[1][threadIdx.x]
                + red[2][threadIdx.x] + red[3][threadIdx.x];
        g4[((size_t)b * 24 + threadIdx.x) * 16 + ch] = t;
    }
}

__global__ void att_k5(const float* __restrict__ g4, float* __restrict__ att) {
    const int b = threadIdx.x;
    if (b >= B_) return;
    float e_[24];
#pragma unroll
    for (int e = 0; e < 24; ++e) {
        const float* p = g4 + ((size_t)b * 24 + e) * 16;
        float t = 0.f;
#pragma unroll
        for (int ch = 0; ch < 16; ++ch) t += p[ch];
        e_[e] = t;
    }
    float nq[4], nk[4];
#pragma unroll
    for (int s = 0; s < 4; ++s) {
        nq[s] = sqrtf(e_[16 + s]) + EPS_F;
        nk[s] = sqrtf(e_[20 + s]) + EPS_F;
    }
#pragma unroll
    for (int s = 0; s < 4; ++s) {
        float e[4], m = -1e30f;
#pragma unroll
        for (int t = 0; t < 4; ++t) {
            e[t] = e_[s * 4 + t] / (nq[s] * nk[t]);
            m = fmaxf(m, e[t]);
        }
        float sum = 0.f;
#pragma unroll
        for (int t = 0; t < 4; ++t) { e[t] = expf(e[t] - m); sum += e[t]; }
#pragma unroll
        for (int t = 0; t < 4; ++t) att[(size_t)(b * 4 + s) * 4 + t] = e[t] / sum;
    }
}

extern "C" void kernel_launch(void* const* d_in, const int* in_sizes, int n_in,
                              void* d_out, int out_size, void* d_ws, size_t ws_size,
                              hipStream_t stream) {
    const float* x     = (const float*)d_in[0];
    const float* wq    = (const float*)d_in[1];
    const float* bq    = (const float*)d_in[2];
    const float* wk    = (const float*)d_in[3];
    const float* bk    = (const float*)d_in[4];
    const float* wv    = (const float*)d_in[5];
    const float* bv    = (const float*)d_in[6];
    const float* gamma = (const float*)d_in[7];
    float* out = (float*)d_out;

    // ws layout (r5 run proved ws_size >= 207MB: big path executed+passed)
    char* ws = (char*)d_ws;
    const size_t qk_elems = (size_t)B_ * S_ * Cq_ * HW_;       // 16,777,216
    ushort_t* Qb      = (ushort_t*)ws;                          // 33.55 MB
    ushort_t* Kb      = Qb + qk_elems;                          // 33.55 MB
    ushort_t* Wqk_pre = Kb + qk_elems;                          // 1.05 MB
    ushort_t* Wvb_pre = Wqk_pre + (size_t)4 * 8 * 256 * 64;     // 4.19 MB
    float*    g4      = (float*)(Wvb_pre + (size_t)4 * 2 * 8 * 256 * 64);
    float*    att     = g4 + 8 * 24 * 16;
    ushort_t* xbfT    = (ushort_t*)(att + 128);                 // 134.2 MB

    prep3<<<768, 256, 0, stream>>>(wq, wk, wv, Wqk_pre, Wvb_pre, g4);
    qk6<<<4096, 512, 0, stream>>>(Wqk_pre, x, bq, bk, Qb, Kb, xbfT);
    gram5<<<dim3(16, 8), 256, 0, stream>>>(Qb, Kb, g4);
    att_k5<<<1, 64, 0, stream>>>(g4, att);
    vblend6<<<2048, 512, 0, stream>>>(Wvb_pre, xbfT, x, bv, att, gamma, out);
}

// Round 7
// 429.655 us; speedup vs baseline: 1.1812x; 1.1812x over previous
//
#include <hip/hip_runtime.h>
#include <hip/hip_bf16.h>

#define EPS_F 1e-10f

typedef short s16x8 __attribute__((ext_vector_type(8)));
typedef float f32x4 __attribute__((ext_vector_type(4)));
typedef unsigned short ushort_t;

constexpr int B_ = 8, S_ = 4, C_ = 512, Cq_ = 128, HW_ = 4096;
constexpr long long D_ = (long long)Cq_ * HW_;

__device__ inline float bf_lo(unsigned int u) { return __uint_as_float(u << 16); }
__device__ inline float bf_hi(unsigned int u) { return __uint_as_float(u & 0xffff0000u); }

__device__ inline ushort_t f2bf(float f) {
    __hip_bfloat16 h = __float2bfloat16(f);
    return *reinterpret_cast<ushort_t*>(&h);
}
__device__ inline unsigned int pack_bf2(float a, float b) {
    return (unsigned int)f2bf(a) | ((unsigned int)f2bf(b) << 16);
}
__device__ inline float dot8(uint4 a, uint4 b) {
    return bf_lo(a.x) * bf_lo(b.x) + bf_hi(a.x) * bf_hi(b.x)
         + bf_lo(a.y) * bf_lo(b.y) + bf_hi(a.y) * bf_hi(b.y)
         + bf_lo(a.z) * bf_lo(b.z) + bf_hi(a.z) * bf_hi(b.z)
         + bf_lo(a.w) * bf_lo(b.w) + bf_hi(a.w) * bf_hi(b.w);
}

#define GLOAD16(gp, lp) __builtin_amdgcn_global_load_lds( \
    (const __attribute__((address_space(1))) unsigned int*)(gp), \
    (__attribute__((address_space(3))) unsigned int*)(lp), 16, 0, 0)

#define VMCNT0 asm volatile("s_waitcnt vmcnt(0)" ::: "memory")
#define LGK0   asm volatile("s_waitcnt lgkmcnt(0)" ::: "memory")
#define MFMA16(a, b, c) __builtin_amdgcn_mfma_f32_16x16x32_bf16(a, b, c, 0, 0, 0)

// swizzle involution over 8 chunk slots, p in [0,64)
#define SWZ(p) ((((p) >> 3) & 7) ^ ((p) & 7))

// ---------------------------------------------------------------------------
// prep3: fp32->bf16 weights, pre-swizzled (chunk slot = c ^ (row&7)) so
// global_load_lds (linear dest) + swizzled ds_read_b128 is conflict-free.
// Also zeroes g4.
// ---------------------------------------------------------------------------
__global__ __launch_bounds__(256) void prep3(
    const float* __restrict__ wq, const float* __restrict__ wk,
    const float* __restrict__ wv,
    ushort_t* __restrict__ Wqk_pre, ushort_t* __restrict__ Wvb_pre,
    float* __restrict__ g4) {
    int gid = blockIdx.x * 256 + threadIdx.x;
    if (gid < 8 * 24 * 16) g4[gid] = 0.f;
    if (gid < 65536) {                      // Wqk chunks
        int s = gid >> 14;
        int kt = (gid >> 11) & 7;
        int row = (gid >> 3) & 255;
        int slot = gid & 7;
        int col = kt * 64 + ((slot ^ (row & 7)) << 3);
        const float* src = (row < 128)
            ? &wq[((size_t)s * 128 + row) * 512 + col]
            : &wk[((size_t)s * 128 + (row - 128)) * 512 + col];
        float4 f0 = *reinterpret_cast<const float4*>(src);
        float4 f1 = *reinterpret_cast<const float4*>(src + 4);
        uint4 o;
        o.x = pack_bf2(f0.x, f0.y); o.y = pack_bf2(f0.z, f0.w);
        o.z = pack_bf2(f1.x, f1.y); o.w = pack_bf2(f1.z, f1.w);
        *reinterpret_cast<uint4*>(Wqk_pre + (size_t)gid * 8) = o;
    } else {                                 // Wvb chunks
        int c2 = gid - 65536;                // < 131072
        int t = c2 >> 15;
        int ct = (c2 >> 14) & 1;
        int kt = (c2 >> 11) & 7;
        int row = (c2 >> 3) & 255;
        int slot = c2 & 7;
        int col = kt * 64 + ((slot ^ (row & 7)) << 3);
        const float* src = &wv[((size_t)t * 512 + ct * 256 + row) * 512 + col];
        float4 f0 = *reinterpret_cast<const float4*>(src);
        float4 f1 = *reinterpret_cast<const float4*>(src + 4);
        uint4 o;
        o.x = pack_bf2(f0.x, f0.y); o.y = pack_bf2(f0.z, f0.w);
        o.z = pack_bf2(f1.x, f1.y); o.w = pack_bf2(f1.z, f1.w);
        *reinterpret_cast<uint4*>(Wvb_pre + (size_t)c2 * 8) = o;
    }
}

// ===========================================================================
// qk6 (unchanged from r6): [Wq;Wk](256x512) @ X[b,t] + bias -> Qb, Kb;
// emits LINEAR transposed bf16 x (xbfT[bt][p][c]) for vblend7.
// ===========================================================================
#define DECLS_COMMON_QK()                                                    \
    const int tid = threadIdx.x;                                             \
    const int w = tid >> 6, lane = tid & 63;                                 \
    const int w4 = w * 4;                                                    \
    const int wr = w >> 1, wc = w & 1;                                       \
    const int li = lane & 15, lk = lane >> 4;                                \
    const int arow = wr * 64;                                                \
    const int bp = wc * 16 + li;                                             \
    int a_sl[2], b_sl[2];                                                    \
    _Pragma("unroll")                                                        \
    for (int h = 0; h < 2; ++h) {                                            \
        a_sl[h] = (((h * 4 + lk) ^ (li & 7)) << 3);                          \
        b_sl[h] = (((h * 4 + lk) ^ SWZ(bp)) << 3);                           \
    }

__global__ __launch_bounds__(512, 4) void qk6(
    const ushort_t* __restrict__ Wqk_pre, const float* __restrict__ x,
    const float* __restrict__ bq, const float* __restrict__ bk,
    ushort_t* __restrict__ Qb, ushort_t* __restrict__ Kb,
    ushort_t* __restrict__ xbfT) {

    const int xcd = blockIdx.x & 7;
    const int idx = blockIdx.x >> 3;          // 0..511
    const int bt = xcd * 4 + (idx >> 7);
    const int s = bt & 3;
    const int p0 = (idx & 127) * 32;

    __shared__ __align__(16) ushort_t AsAll[2 * 16384];  // 64KB
    __shared__ __align__(16) ushort_t BsAll[2 * 2048];   // 8KB

    DECLS_COMMON_QK();

    const int sk = tid >> 3, spb = (tid & 7) * 4;
    const int ep = tid >> 3, esl = tid & 7;
    const int ec = esl ^ SWZ(ep);

    const float* Bx = x + (size_t)bt * C_ * HW_ + p0 + spb;

    f32x4 acc[4];
#pragma unroll
    for (int mf = 0; mf < 4; ++mf) acc[mf] = 0.f;

    float4 nb;

#define STAGE_A6(T, BUF)                                                     \
    { const ushort_t* _tp = Wqk_pre + ((size_t)(s * 8 + (T)) << 14);         \
      ushort_t* _ld = &AsAll[(BUF) * 16384];                                 \
      _Pragma("unroll")                                                      \
      for (int _i = 0; _i < 4; ++_i)                                         \
          GLOAD16(_tp + ((w4 + _i) << 9) + (lane << 3),                      \
                  _ld + ((w4 + _i) << 9)); }

#define LOAD_B6(T) nb = *reinterpret_cast<const float4*>(Bx + (size_t)((T) * 64 + sk) * HW_)

#define WRITE_B6(BUF)                                                        \
    { float _vv[4] = {nb.x, nb.y, nb.z, nb.w};                               \
      _Pragma("unroll")                                                      \
      for (int _j = 0; _j < 4; ++_j) {                                       \
          int _p = spb + _j;                                                 \
          BsAll[(BUF) * 2048 + _p * 64 + (((sk >> 3) ^ SWZ(_p)) << 3)        \
                + (sk & 7)] = f2bf(_vv[_j]);                                 \
      } }

#define EMIT6(T, BUF)                                                        \
    if (w < 4) {                                                             \
        s16x8 _ev = *reinterpret_cast<const s16x8*>(&BsAll[(BUF) * 2048 + tid * 8]); \
        *reinterpret_cast<s16x8*>(                                           \
            xbfT + ((size_t)bt * HW_ + p0 + ep) * 512 + (T) * 64 + ec * 8) = _ev; \
    }

#define COMPUTE6Q(BUF)                                                       \
    { const int _ab = (BUF) * 16384, _bb = (BUF) * 2048;                     \
      _Pragma("unroll")                                                      \
      for (int h = 0; h < 2; ++h) {                                          \
          s16x8 af0 = *reinterpret_cast<const s16x8*>(                       \
              &AsAll[_ab + (arow + 0 * 16 + li) * 64 + a_sl[h]]);            \
          s16x8 af1 = *reinterpret_cast<const s16x8*>(                       \
              &AsAll[_ab + (arow + 1 * 16 + li) * 64 + a_sl[h]]);            \
          s16x8 af2 = *reinterpret_cast<const s16x8*>(                       \
              &AsAll[_ab + (arow + 2 * 16 + li) * 64 + a_sl[h]]);            \
          s16x8 af3 = *reinterpret_cast<const s16x8*>(                       \
              &AsAll[_ab + (arow + 3 * 16 + li) * 64 + a_sl[h]]);            \
          s16x8 bf = *reinterpret_cast<const s16x8*>(                        \
              &BsAll[_bb + bp * 64 + b_sl[h]]);                              \
          __builtin_amdgcn_s_setprio(1);                                     \
          acc[0] = MFMA16(af0, bf, acc[0]);                                  \
          acc[1] = MFMA16(af1, bf, acc[1]);                                  \
          acc[2] = MFMA16(af2, bf, acc[2]);                                  \
          acc[3] = MFMA16(af3, bf, acc[3]);                                  \
          __builtin_amdgcn_s_setprio(0);                                     \
      } }

    LOAD_B6(0);
    STAGE_A6(0, 0);
    WRITE_B6(0);
    VMCNT0; LGK0;
    __builtin_amdgcn_s_barrier();

#pragma unroll
    for (int t = 0; t < 8; ++t) {
        if (t < 7) { LOAD_B6(t + 1); STAGE_A6(t + 1, (t + 1) & 1); }
        EMIT6(t, t & 1);
        COMPUTE6Q(t & 1);
        if (t < 7) {
            WRITE_B6((t + 1) & 1);
            VMCNT0; LGK0;
            __builtin_amdgcn_s_barrier();
        }
    }

#undef STAGE_A6
#undef LOAD_B6
#undef WRITE_B6
#undef EMIT6
#undef COMPUTE6Q

#pragma unroll
    for (int mf = 0; mf < 4; ++mf) {
#pragma unroll
        for (int r = 0; r < 4; ++r) {
            int m = wr * 64 + mf * 16 + lk * 4 + r;
            float bias = (m < 128) ? bq[s * 128 + m] : bk[s * 128 + (m - 128)];
            int p = p0 + wc * 16 + li;
            float vv = acc[mf][r] + bias;
            if (m < 128)
                Qb[(size_t)bt * D_ + (size_t)m * HW_ + p] = f2bf(vv);
            else
                Kb[(size_t)bt * D_ + (size_t)(m - 128) * HW_ + p] = f2bf(vv);
        }
    }
}

// ===========================================================================
// vblend7: m97-occupancy-regime fused V-GEMM + blend + bias + gamma + resid.
// 256 thr = 4 waves (2x2), block tile 64c x 64p, wave tile 32x32, BK=64.
// LDS 32KB/block (A,B double-buffered, both via global_load_lds) ->
// 4 blocks/CU; launch_bounds(256,4) caps regs at 128 -> 16 waves/CU with
// 4 INDEPENDENT barrier groups (cross-block latency hiding, m97 model).
// A LDS [64c][slot8][8k] slot=kchunk^(row&7) (pre-swizzled Wvb_pre slice);
// B LDS [64p][slot8][8k] slot=kchunk^SWZ(p) (inverse-swizzled linear xbfT).
// ===========================================================================
__global__ __launch_bounds__(256, 4) void vblend7(
    const ushort_t* __restrict__ Wvb_pre, const ushort_t* __restrict__ xbfT,
    const float* __restrict__ x, const float* __restrict__ bv,
    const float* __restrict__ att, const float* __restrict__ gamma,
    float* __restrict__ out) {

    // 4096 blocks: xcd = b (8); idx: cblk (8) x pblk (64)
    const int b = blockIdx.x & 7;
    const int idx = blockIdx.x >> 3;        // 0..511
    const int cblk = idx >> 6;              // 0..7
    const int p0 = (idx & 63) * 64;
    const int ct = cblk >> 2;               // 256-row panel half
    const int csub = cblk & 3;              // 64-row slice within panel

    __shared__ __align__(16) ushort_t AsAll[2 * 4096];   // 16KB
    __shared__ __align__(16) ushort_t BsAll[2 * 4096];   // 16KB

    const int tid = threadIdx.x;
    const int w = tid >> 6, lane = tid & 63;
    const int wr2 = w >> 1, wc2 = w & 1;
    const int li = lane & 15, lk = lane >> 4;

    // fragment read offsets
    int a_sl[2], b_sl[2];
    const int bp = wc2 * 32 + li;           // B p-base for nf=0 (nf=1: +16)
    const int bp1 = bp + 16;
    int b_sl1[2];
#pragma unroll
    for (int h = 0; h < 2; ++h) {
        a_sl[h] = (((h * 4 + lk) ^ (li & 7)) << 3);
        b_sl[h] = (((h * 4 + lk) ^ SWZ(bp)) << 3);
        b_sl1[h] = (((h * 4 + lk) ^ SWZ(bp1)) << 3);
    }

    // att weights as block-uniform scalars
    float attv[16];
#pragma unroll
    for (int i = 0; i < 16; ++i)
        attv[i] = __uint_as_float(__builtin_amdgcn_readfirstlane(
            __float_as_uint(att[b * 16 + i])));

    // staging maps (2 chunks each for A and B per thread per step)
    // A: chunk ch = tid + i*256: row=ch>>3, slot=ch&7 (pre-swizzled source)
    // B: chunk ch = tid + i*256: p=ch>>3, sl=ch&7, data kchunk = sl^SWZ(p)
    const int bst_p0 = tid >> 3, bst_sl0 = tid & 7;
    const int bst_c0 = bst_sl0 ^ SWZ(bst_p0);
    const int bst_p1 = (tid + 256) >> 3, bst_sl1 = tid & 7;
    const int bst_c1 = bst_sl1 ^ SWZ(bst_p1);

    f32x4 acc[2][2];
    f32x4 mst[4][2][2];
#pragma unroll
    for (int mf = 0; mf < 2; ++mf)
#pragma unroll
        for (int nf = 0; nf < 2; ++nf) acc[mf][nf] = 0.f;
#pragma unroll
    for (int so = 0; so < 4; ++so)
#pragma unroll
        for (int mf = 0; mf < 2; ++mf)
#pragma unroll
            for (int nf = 0; nf < 2; ++nf) mst[so][mf][nf] = 0.f;

#define STAGE7(TS, BUF)                                                      \
    {   const int _t = (TS) >> 3, _kt = (TS) & 7;                            \
        const ushort_t* _ap = Wvb_pre +                                      \
            (((size_t)(_t * 2 + ct) * 8 + _kt) << 14) + (csub << 12);        \
        ushort_t* _al = &AsAll[(BUF) * 4096];                                \
        GLOAD16(_ap + (size_t)(w << 9) + (size_t)((lane & 63) << 3),         \
                _al + (w << 9));                                             \
        GLOAD16(_ap + 2048 + (size_t)(w << 9) + (size_t)(lane << 3),         \
                _al + 2048 + (w << 9));                                      \
        const ushort_t* _bb = xbfT + ((size_t)(b * 4 + _t) * HW_);           \
        GLOAD16(_bb + ((size_t)(p0 + bst_p0)) * 512 + _kt * 64 + bst_c0 * 8, \
                &BsAll[(BUF) * 4096 + (w << 9)]);                            \
        GLOAD16(_bb + ((size_t)(p0 + bst_p1)) * 512 + _kt * 64 + bst_c1 * 8, \
                &BsAll[(BUF) * 4096 + 2048 + (w << 9)]);                     \
    }

#define COMPUTE7(BUF)                                                       \
    {   const int _ab = (BUF) * 4096, _bbf = (BUF) * 4096;                  \
        _Pragma("unroll")                                                    \
        for (int h = 0; h < 2; ++h) {                                        \
            s16x8 af0 = *reinterpret_cast<const s16x8*>(                     \
                &AsAll[_ab + (wr2 * 32 + 0 * 16 + li) * 64 + a_sl[h]]);      \
            s16x8 af1 = *reinterpret_cast<const s16x8*>(                     \
                &AsAll[_ab + (wr2 * 32 + 1 * 16 + li) * 64 + a_sl[h]]);      \
            s16x8 bf0 = *reinterpret_cast<const s16x8*>(                     \
                &BsAll[_bbf + bp * 64 + b_sl[h]]);                           \
            s16x8 bf1 = *reinterpret_cast<const s16x8*>(                     \
                &BsAll[_bbf + bp1 * 64 + b_sl1[h]]);                         \
            __builtin_amdgcn_s_setprio(1);                                   \
            acc[0][0] = MFMA16(af0, bf0, acc[0][0]);                         \
            acc[0][1] = MFMA16(af0, bf1, acc[0][1]);                         \
            acc[1][0] = MFMA16(af1, bf0, acc[1][0]);                         \
            acc[1][1] = MFMA16(af1, bf1, acc[1][1]);                         \
            __builtin_amdgcn_s_setprio(0);                                   \
        } }

#define BLEND7(T2)                                                           \
    { _Pragma("unroll")                                                      \
      for (int _so = 0; _so < 4; ++_so)                                      \
          _Pragma("unroll")                                                  \
          for (int _mf = 0; _mf < 2; ++_mf)                                  \
              _Pragma("unroll")                                              \
              for (int _nf = 0; _nf < 2; ++_nf)                              \
                  mst[_so][_mf][_nf] += attv[_so * 4 + (T2)] * acc[_mf][_nf];\
      _Pragma("unroll")                                                      \
      for (int _mf = 0; _mf < 2; ++_mf)                                      \
          _Pragma("unroll")                                                  \
          for (int _nf = 0; _nf < 2; ++_nf) acc[_mf][_nf] = 0.f; }

    // prologue
    STAGE7(0, 0);
    VMCNT0;
    __builtin_amdgcn_s_barrier();

#pragma unroll
    for (int ts = 0; ts < 32; ++ts) {
        if (ts < 31) STAGE7(ts + 1, (ts + 1) & 1);
        COMPUTE7(ts & 1);
        if (ts == 7)  BLEND7(0);
        if (ts == 15) BLEND7(1);
        if (ts == 23) BLEND7(2);
        if (ts == 31) BLEND7(3);
        if (ts < 31) {
            VMCNT0;
            __builtin_amdgcn_s_barrier();
        }
    }

#undef STAGE7
#undef COMPUTE7
#undef BLEND7

    // epilogue: out = gm*(mst + sum_t att*bv) + x
    const float gm = gamma[0];
    const int c0 = cblk * 64;
#pragma unroll
    for (int mf = 0; mf < 2; ++mf) {
#pragma unroll
        for (int r = 0; r < 4; ++r) {
            int c = c0 + wr2 * 32 + mf * 16 + lk * 4 + r;
            float bvv[4];
#pragma unroll
            for (int t = 0; t < 4; ++t) bvv[t] = bv[(size_t)t * 512 + c];
#pragma unroll
            for (int so = 0; so < 4; ++so) {
                float bsum = attv[so * 4 + 0] * bvv[0] + attv[so * 4 + 1] * bvv[1]
                           + attv[so * 4 + 2] * bvv[2] + attv[so * 4 + 3] * bvv[3];
#pragma unroll
                for (int nf = 0; nf < 2; ++nf) {
                    int p = p0 + wc2 * 32 + nf * 16 + li;
                    size_t off = ((size_t)(b * 4 + so) * C_ + c) * HW_ + p;
                    out[off] = gm * (mst[so][mf][nf][r] + bsum) + x[off];
                }
            }
        }
    }
}

// ---------------------------------------------------------------------------
// gram5: all 24 reductions per (b, D/16-slice); Q/K read once. Deterministic.
// ---------------------------------------------------------------------------
__global__ __launch_bounds__(256) void gram5(
    const ushort_t* __restrict__ Q, const ushort_t* __restrict__ K,
    float* __restrict__ g4) {

    const int ch = blockIdx.x;       // 0..15
    const int b  = blockIdx.y;       // 0..7
    const size_t base = (size_t)ch * (D_ / 16);

    const uint4* qv[4];
    const uint4* kv[4];
#pragma unroll
    for (int s = 0; s < 4; ++s) {
        qv[s] = reinterpret_cast<const uint4*>(Q + (size_t)(b * 4 + s) * D_ + base);
        kv[s] = reinterpret_cast<const uint4*>(K + (size_t)(b * 4 + s) * D_ + base);
    }

    float accr[24];
#pragma unroll
    for (int e = 0; e < 24; ++e) accr[e] = 0.f;

    const int n8 = (int)(D_ / 16 / 8);
    for (int i = threadIdx.x; i < n8; i += 256) {
        uint4 qa[4], ka[4];
#pragma unroll
        for (int s = 0; s < 4; ++s) { qa[s] = qv[s][i]; ka[s] = kv[s][i]; }
#pragma unroll
        for (int s = 0; s < 4; ++s) {
#pragma unroll
            for (int u = 0; u < 4; ++u) accr[s * 4 + u] += dot8(qa[s], ka[u]);
            accr[16 + s] += dot8(qa[s], qa[s]);
            accr[20 + s] += dot8(ka[s], ka[s]);
        }
    }

    __shared__ float red[4][24];
    const int lane = threadIdx.x & 63, wid = threadIdx.x >> 6;
#pragma unroll
    for (int e = 0; e < 24; ++e) {
        float v = accr[e];
#pragma unroll
        for (int o = 32; o > 0; o >>= 1) v += __shfl_down(v, o);
        if (lane == 0) red[wid][e] = v;
    }
    __syncthreads();
    if (threadIdx.x < 24) {
        float t = red[0][threadIdx.x] + red[1][threadIdx.x]
                + red[2][threadIdx.x] + red[3][threadIdx.x];
        g4[((size_t)b * 24 + threadIdx.x) * 16 + ch] = t;
    }
}

__global__ void att_k5(const float* __restrict__ g4, float* __restrict__ att) {
    const int b = threadIdx.x;
    if (b >= B_) return;
    float e_[24];
#pragma unroll
    for (int e = 0; e < 24; ++e) {
        const float* p = g4 + ((size_t)b * 24 + e) * 16;
        float t = 0.f;
#pragma unroll
        for (int ch = 0; ch < 16; ++ch) t += p[ch];
        e_[e] = t;
    }
    float nq[4], nk[4];
#pragma unroll
    for (int s = 0; s < 4; ++s) {
        nq[s] = sqrtf(e_[16 + s]) + EPS_F;
        nk[s] = sqrtf(e_[20 + s]) + EPS_F;
    }
#pragma unroll
    for (int s = 0; s < 4; ++s) {
        float e[4], m = -1e30f;
#pragma unroll
        for (int t = 0; t < 4; ++t) {
            e[t] = e_[s * 4 + t] / (nq[s] * nk[t]);
            m = fmaxf(m, e[t]);
        }
        float sum = 0.f;
#pragma unroll
        for (int t = 0; t < 4; ++t) { e[t] = expf(e[t] - m); sum += e[t]; }
#pragma unroll
        for (int t = 0; t < 4; ++t) att[(size_t)(b * 4 + s) * 4 + t] = e[t] / sum;
    }
}

extern "C" void kernel_launch(void* const* d_in, const int* in_sizes, int n_in,
                              void* d_out, int out_size, void* d_ws, size_t ws_size,
                              hipStream_t stream) {
    const float* x     = (const float*)d_in[0];
    const float* wq    = (const float*)d_in[1];
    const float* bq    = (const float*)d_in[2];
    const float* wk    = (const float*)d_in[3];
    const float* bk    = (const float*)d_in[4];
    const float* wv    = (const float*)d_in[5];
    const float* bv    = (const float*)d_in[6];
    const float* gamma = (const float*)d_in[7];
    float* out = (float*)d_out;

    char* ws = (char*)d_ws;
    const size_t qk_elems = (size_t)B_ * S_ * Cq_ * HW_;       // 16,777,216
    ushort_t* Qb      = (ushort_t*)ws;                          // 33.55 MB
    ushort_t* Kb      = Qb + qk_elems;                          // 33.55 MB
    ushort_t* Wqk_pre = Kb + qk_elems;                          // 1.05 MB
    ushort_t* Wvb_pre = Wqk_pre + (size_t)4 * 8 * 256 * 64;     // 4.19 MB
    float*    g4      = (float*)(Wvb_pre + (size_t)4 * 2 * 8 * 256 * 64);
    float*    att     = g4 + 8 * 24 * 16;
    ushort_t* xbfT    = (ushort_t*)(att + 128);                 // 134.2 MB

    prep3<<<768, 256, 0, stream>>>(wq, wk, wv, Wqk_pre, Wvb_pre, g4);
    qk6<<<4096, 512, 0, stream>>>(Wqk_pre, x, bq, bk, Qb, Kb, xbfT);
    gram5<<<dim3(16, 8), 256, 0, stream>>>(Qb, Kb, g4);
    att_k5<<<1, 64, 0, stream>>>(g4, att);
    vblend7<<<4096, 256, 0, stream>>>(Wvb_pre, xbfT, x, bv, att, gamma, out);
}

// Round 8
// 405.616 us; speedup vs baseline: 1.2512x; 1.0593x over previous
//
#include <hip/hip_runtime.h>
#include <hip/hip_bf16.h>

#define EPS_F 1e-10f

typedef short s16x8 __attribute__((ext_vector_type(8)));
typedef float f32x4 __attribute__((ext_vector_type(4)));
typedef unsigned short ushort_t;

constexpr int B_ = 8, S_ = 4, C_ = 512, Cq_ = 128, HW_ = 4096;
constexpr long long D_ = (long long)Cq_ * HW_;

__device__ inline float bf_lo(unsigned int u) { return __uint_as_float(u << 16); }
__device__ inline float bf_hi(unsigned int u) { return __uint_as_float(u & 0xffff0000u); }

__device__ inline ushort_t f2bf(float f) {
    __hip_bfloat16 h = __float2bfloat16(f);
    return *reinterpret_cast<ushort_t*>(&h);
}
__device__ inline unsigned int pack_bf2(float a, float b) {
    return (unsigned int)f2bf(a) | ((unsigned int)f2bf(b) << 16);
}
__device__ inline float dot8(uint4 a, uint4 b) {
    return bf_lo(a.x) * bf_lo(b.x) + bf_hi(a.x) * bf_hi(b.x)
         + bf_lo(a.y) * bf_lo(b.y) + bf_hi(a.y) * bf_hi(b.y)
         + bf_lo(a.z) * bf_lo(b.z) + bf_hi(a.z) * bf_hi(b.z)
         + bf_lo(a.w) * bf_lo(b.w) + bf_hi(a.w) * bf_hi(b.w);
}

#define GLOAD16(gp, lp) __builtin_amdgcn_global_load_lds( \
    (const __attribute__((address_space(1))) unsigned int*)(gp), \
    (__attribute__((address_space(3))) unsigned int*)(lp), 16, 0, 0)

#define VMCNT0 asm volatile("s_waitcnt vmcnt(0)" ::: "memory")
#define LGK0   asm volatile("s_waitcnt lgkmcnt(0)" ::: "memory")
#define MFMA16(a, b, c) __builtin_amdgcn_mfma_f32_16x16x32_bf16(a, b, c, 0, 0, 0)

// swizzle involution over 8 chunk slots, p in [0,64)
#define SWZ(p) ((((p) >> 3) & 7) ^ ((p) & 7))

// ---------------------------------------------------------------------------
// prep3: fp32->bf16 weights, pre-swizzled (chunk slot = c ^ (row&7)) so
// global_load_lds (linear dest) + swizzled ds_read_b128 is conflict-free.
// Also zeroes g4.
// ---------------------------------------------------------------------------
__global__ __launch_bounds__(256) void prep3(
    const float* __restrict__ wq, const float* __restrict__ wk,
    const float* __restrict__ wv,
    ushort_t* __restrict__ Wqk_pre, ushort_t* __restrict__ Wvb_pre,
    float* __restrict__ g4) {
    int gid = blockIdx.x * 256 + threadIdx.x;
    if (gid < 8 * 24 * 16) g4[gid] = 0.f;
    if (gid < 65536) {                      // Wqk chunks
        int s = gid >> 14;
        int kt = (gid >> 11) & 7;
        int row = (gid >> 3) & 255;
        int slot = gid & 7;
        int col = kt * 64 + ((slot ^ (row & 7)) << 3);
        const float* src = (row < 128)
            ? &wq[((size_t)s * 128 + row) * 512 + col]
            : &wk[((size_t)s * 128 + (row - 128)) * 512 + col];
        float4 f0 = *reinterpret_cast<const float4*>(src);
        float4 f1 = *reinterpret_cast<const float4*>(src + 4);
        uint4 o;
        o.x = pack_bf2(f0.x, f0.y); o.y = pack_bf2(f0.z, f0.w);
        o.z = pack_bf2(f1.x, f1.y); o.w = pack_bf2(f1.z, f1.w);
        *reinterpret_cast<uint4*>(Wqk_pre + (size_t)gid * 8) = o;
    } else {                                 // Wvb chunks
        int c2 = gid - 65536;                // < 131072
        int t = c2 >> 15;
        int ct = (c2 >> 14) & 1;
        int kt = (c2 >> 11) & 7;
        int row = (c2 >> 3) & 255;
        int slot = c2 & 7;
        int col = kt * 64 + ((slot ^ (row & 7)) << 3);
        const float* src = &wv[((size_t)t * 512 + ct * 256 + row) * 512 + col];
        float4 f0 = *reinterpret_cast<const float4*>(src);
        float4 f1 = *reinterpret_cast<const float4*>(src + 4);
        uint4 o;
        o.x = pack_bf2(f0.x, f0.y); o.y = pack_bf2(f0.z, f0.w);
        o.z = pack_bf2(f1.x, f1.y); o.w = pack_bf2(f1.z, f1.w);
        *reinterpret_cast<uint4*>(Wvb_pre + (size_t)c2 * 8) = o;
    }
}

// ===========================================================================
// qk8: [Wq;Wk](256x512) @ X[b,t] + bias -> Qb, Kb; emits transposed bf16 x.
// Block = 128o x 32p, BK=64, 512 thr = 8 waves (4 wr x 2 wc), wave 32o x 16p.
// LDS 40KB -> 4 blocks/CU; launch_bounds(512,8) caps 64 VGPR -> 32 waves/CU.
// o innermost in grid -> co-resident o-pairs share the x B-tile (L2).
// ===========================================================================
__global__ __launch_bounds__(512, 8) void qk8(
    const ushort_t* __restrict__ Wqk_pre, const float* __restrict__ x,
    const float* __restrict__ bq, const float* __restrict__ bk,
    ushort_t* __restrict__ Qb, ushort_t* __restrict__ Kb,
    ushort_t* __restrict__ xbfT) {

    // 8192 blocks: xcd = blk&7; idx: btl(4) x p(128) x o(2), o innermost
    const int xcd = blockIdx.x & 7;
    const int idx = blockIdx.x >> 3;          // 0..1023
    const int bt = xcd * 4 + (idx >> 8);
    const int s = bt & 3;
    const int pb = (idx >> 1) & 127;
    const int ob = idx & 1;
    const int p0 = pb * 32;

    __shared__ __align__(16) ushort_t AsAll[2 * 8192];   // 32KB
    __shared__ __align__(16) ushort_t BsAll[2 * 2048];   // 8KB

    const int tid = threadIdx.x;
    const int w = tid >> 6, lane = tid & 63;
    const int wr = w >> 1, wc = w & 1;
    const int li = lane & 15, lk = lane >> 4;
    const int arow = wr * 32;
    const int bp = wc * 16 + li;
    int a_sl[2], b_sl[2];
#pragma unroll
    for (int h = 0; h < 2; ++h) {
        a_sl[h] = (((h * 4 + lk) ^ (li & 7)) << 3);
        b_sl[h] = (((h * 4 + lk) ^ SWZ(bp)) << 3);
    }

    // B staging: thread -> k=tid>>3 (0..63), p-base=(tid&7)*4
    const int sk = tid >> 3, spb = (tid & 7) * 4;
    // emission (threads 0..255): LDS chunk (p=tid>>3, slot=tid&7)
    const int ep = tid >> 3, esl = tid & 7;
    const int ec = esl ^ SWZ(ep);

    const float* Bx = x + (size_t)bt * C_ * HW_ + p0 + spb;

    f32x4 acc[2];
    acc[0] = 0.f; acc[1] = 0.f;
    float4 nb;

#define STAGE_A8(T, BUF)                                                     \
    { const ushort_t* _tp = Wqk_pre + ((size_t)(s * 8 + (T)) << 14)          \
                            + (ob << 13);                                    \
      ushort_t* _ld = &AsAll[(BUF) * 8192];                                  \
      _Pragma("unroll")                                                      \
      for (int _i = 0; _i < 2; ++_i)                                         \
          GLOAD16(_tp + ((w * 2 + _i) << 9) + (lane << 3),                   \
                  _ld + ((w * 2 + _i) << 9)); }

#define LOAD_B8(T) nb = *reinterpret_cast<const float4*>(Bx + (size_t)((T) * 64 + sk) * HW_)

#define WRITE_B8(BUF)                                                        \
    { float _vv[4] = {nb.x, nb.y, nb.z, nb.w};                               \
      _Pragma("unroll")                                                      \
      for (int _j = 0; _j < 4; ++_j) {                                       \
          int _p = spb + _j;                                                 \
          BsAll[(BUF) * 2048 + _p * 64 + (((sk >> 3) ^ SWZ(_p)) << 3)        \
                + (sk & 7)] = f2bf(_vv[_j]);                                 \
      } }

#define EMIT8(T, BUF)                                                        \
    if (ob == 0 && w < 4) {                                                  \
        s16x8 _ev = *reinterpret_cast<const s16x8*>(&BsAll[(BUF) * 2048 + tid * 8]); \
        *reinterpret_cast<s16x8*>(                                           \
            xbfT + ((size_t)bt * HW_ + p0 + ep) * 512 + (T) * 64 + ec * 8) = _ev; \
    }

#define COMPUTE8(BUF)                                                        \
    { const int _ab = (BUF) * 8192, _bb = (BUF) * 2048;                      \
      _Pragma("unroll")                                                      \
      for (int h = 0; h < 2; ++h) {                                          \
          s16x8 af0 = *reinterpret_cast<const s16x8*>(                       \
              &AsAll[_ab + (arow + 0 * 16 + li) * 64 + a_sl[h]]);            \
          s16x8 af1 = *reinterpret_cast<const s16x8*>(                       \
              &AsAll[_ab + (arow + 1 * 16 + li) * 64 + a_sl[h]]);            \
          s16x8 bf = *reinterpret_cast<const s16x8*>(                        \
              &BsAll[_bb + bp * 64 + b_sl[h]]);                              \
          __builtin_amdgcn_s_setprio(1);                                     \
          acc[0] = MFMA16(af0, bf, acc[0]);                                  \
          acc[1] = MFMA16(af1, bf, acc[1]);                                  \
          __builtin_amdgcn_s_setprio(0);                                     \
      } }

    // prologue
    LOAD_B8(0);
    STAGE_A8(0, 0);
    WRITE_B8(0);
    VMCNT0; LGK0;
    __builtin_amdgcn_s_barrier();

#pragma unroll
    for (int t = 0; t < 8; ++t) {
        if (t < 7) { LOAD_B8(t + 1); STAGE_A8(t + 1, (t + 1) & 1); }
        EMIT8(t, t & 1);
        COMPUTE8(t & 1);
        if (t < 7) {
            WRITE_B8((t + 1) & 1);
            VMCNT0; LGK0;
            __builtin_amdgcn_s_barrier();
        }
    }

#undef STAGE_A8
#undef LOAD_B8
#undef WRITE_B8
#undef EMIT8
#undef COMPUTE8

    // epilogue: +bias, ob selects Q vs K (block-uniform)
    ushort_t* outp = ob ? Kb : Qb;
    const float* biasp = ob ? (bk + s * 128) : (bq + s * 128);
#pragma unroll
    for (int mf = 0; mf < 2; ++mf) {
#pragma unroll
        for (int r = 0; r < 4; ++r) {
            int m = arow + mf * 16 + lk * 4 + r;     // 0..127 within half
            float vv = acc[mf][r] + biasp[m];
            int p = p0 + wc * 16 + li;
            outp[(size_t)bt * D_ + (size_t)m * HW_ + p] = f2bf(vv);
        }
    }
}

// ===========================================================================
// vblend8: fused V-GEMM + blend + bias + gamma + residual (vblend7 structure;
// ONLY change: cblk innermost so co-resident blocks share the B-tile in L2,
// streaming different W rows -- cuts L3-path B traffic ~8x).
// ===========================================================================
__global__ __launch_bounds__(256, 4) void vblend8(
    const ushort_t* __restrict__ Wvb_pre, const ushort_t* __restrict__ xbfT,
    const float* __restrict__ x, const float* __restrict__ bv,
    const float* __restrict__ att, const float* __restrict__ gamma,
    float* __restrict__ out) {

    // 4096 blocks: xcd = b (8); idx: pblk(64) x cblk(8), cblk innermost
    const int b = blockIdx.x & 7;
    const int idx = blockIdx.x >> 3;        // 0..511
    const int cblk = idx & 7;               // 0..7  (inner -> shared B)
    const int p0 = (idx >> 3) * 64;         // 0..63 p-tiles
    const int ct = cblk >> 2;
    const int csub = cblk & 3;

    __shared__ __align__(16) ushort_t AsAll[2 * 4096];   // 16KB
    __shared__ __align__(16) ushort_t BsAll[2 * 4096];   // 16KB

    const int tid = threadIdx.x;
    const int w = tid >> 6, lane = tid & 63;
    const int wr2 = w >> 1, wc2 = w & 1;
    const int li = lane & 15, lk = lane >> 4;

    int a_sl[2], b_sl[2];
    const int bp = wc2 * 32 + li;
    const int bp1 = bp + 16;
    int b_sl1[2];
#pragma unroll
    for (int h = 0; h < 2; ++h) {
        a_sl[h] = (((h * 4 + lk) ^ (li & 7)) << 3);
        b_sl[h] = (((h * 4 + lk) ^ SWZ(bp)) << 3);
        b_sl1[h] = (((h * 4 + lk) ^ SWZ(bp1)) << 3);
    }

    float attv[16];
#pragma unroll
    for (int i = 0; i < 16; ++i)
        attv[i] = __uint_as_float(__builtin_amdgcn_readfirstlane(
            __float_as_uint(att[b * 16 + i])));

    const int bst_p0 = tid >> 3, bst_sl0 = tid & 7;
    const int bst_c0 = bst_sl0 ^ SWZ(bst_p0);
    const int bst_p1 = (tid + 256) >> 3, bst_sl1 = tid & 7;
    const int bst_c1 = bst_sl1 ^ SWZ(bst_p1);

    f32x4 acc[2][2];
    f32x4 mst[4][2][2];
#pragma unroll
    for (int mf = 0; mf < 2; ++mf)
#pragma unroll
        for (int nf = 0; nf < 2; ++nf) acc[mf][nf] = 0.f;
#pragma unroll
    for (int so = 0; so < 4; ++so)
#pragma unroll
        for (int mf = 0; mf < 2; ++mf)
#pragma unroll
            for (int nf = 0; nf < 2; ++nf) mst[so][mf][nf] = 0.f;

#define STAGE7(TS, BUF)                                                      \
    {   const int _t = (TS) >> 3, _kt = (TS) & 7;                            \
        const ushort_t* _ap = Wvb_pre +                                      \
            (((size_t)(_t * 2 + ct) * 8 + _kt) << 14) + (csub << 12);        \
        ushort_t* _al = &AsAll[(BUF) * 4096];                                \
        GLOAD16(_ap + (size_t)(w << 9) + (size_t)(lane << 3),                \
                _al + (w << 9));                                             \
        GLOAD16(_ap + 2048 + (size_t)(w << 9) + (size_t)(lane << 3),         \
                _al + 2048 + (w << 9));                                      \
        const ushort_t* _bb = xbfT + ((size_t)(b * 4 + _t) * HW_);           \
        GLOAD16(_bb + ((size_t)(p0 + bst_p0)) * 512 + _kt * 64 + bst_c0 * 8, \
                &BsAll[(BUF) * 4096 + (w << 9)]);                            \
        GLOAD16(_bb + ((size_t)(p0 + bst_p1)) * 512 + _kt * 64 + bst_c1 * 8, \
                &BsAll[(BUF) * 4096 + 2048 + (w << 9)]);                     \
    }

#define COMPUTE7(BUF)                                                       \
    {   const int _ab = (BUF) * 4096, _bbf = (BUF) * 4096;                  \
        _Pragma("unroll")                                                    \
        for (int h = 0; h < 2; ++h) {                                        \
            s16x8 af0 = *reinterpret_cast<const s16x8*>(                     \
                &AsAll[_ab + (wr2 * 32 + 0 * 16 + li) * 64 + a_sl[h]]);      \
            s16x8 af1 = *reinterpret_cast<const s16x8*>(                     \
                &AsAll[_ab + (wr2 * 32 + 1 * 16 + li) * 64 + a_sl[h]]);      \
            s16x8 bf0 = *reinterpret_cast<const s16x8*>(                     \
                &BsAll[_bbf + bp * 64 + b_sl[h]]);                           \
            s16x8 bf1 = *reinterpret_cast<const s16x8*>(                     \
                &BsAll[_bbf + bp1 * 64 + b_sl1[h]]);                         \
            __builtin_amdgcn_s_setprio(1);                                   \
            acc[0][0] = MFMA16(af0, bf0, acc[0][0]);                         \
            acc[0][1] = MFMA16(af0, bf1, acc[0][1]);                         \
            acc[1][0] = MFMA16(af1, bf0, acc[1][0]);                         \
            acc[1][1] = MFMA16(af1, bf1, acc[1][1]);                         \
            __builtin_amdgcn_s_setprio(0);                                   \
        } }

#define BLEND7(T2)                                                           \
    { _Pragma("unroll")                                                      \
      for (int _so = 0; _so < 4; ++_so)                                      \
          _Pragma("unroll")                                                  \
          for (int _mf = 0; _mf < 2; ++_mf)                                  \
              _Pragma("unroll")                                              \
              for (int _nf = 0; _nf < 2; ++_nf)                              \
                  mst[_so][_mf][_nf] += attv[_so * 4 + (T2)] * acc[_mf][_nf];\
      _Pragma("unroll")                                                      \
      for (int _mf = 0; _mf < 2; ++_mf)                                      \
          _Pragma("unroll")                                                  \
          for (int _nf = 0; _nf < 2; ++_nf) acc[_mf][_nf] = 0.f; }

    STAGE7(0, 0);
    VMCNT0;
    __builtin_amdgcn_s_barrier();

#pragma unroll
    for (int ts = 0; ts < 32; ++ts) {
        if (ts < 31) STAGE7(ts + 1, (ts + 1) & 1);
        COMPUTE7(ts & 1);
        if (ts == 7)  BLEND7(0);
        if (ts == 15) BLEND7(1);
        if (ts == 23) BLEND7(2);
        if (ts == 31) BLEND7(3);
        if (ts < 31) {
            VMCNT0;
            __builtin_amdgcn_s_barrier();
        }
    }

#undef STAGE7
#undef COMPUTE7
#undef BLEND7

    const float gm = gamma[0];
    const int c0 = cblk * 64;
#pragma unroll
    for (int mf = 0; mf < 2; ++mf) {
#pragma unroll
        for (int r = 0; r < 4; ++r) {
            int c = c0 + wr2 * 32 + mf * 16 + lk * 4 + r;
            float bvv[4];
#pragma unroll
            for (int t = 0; t < 4; ++t) bvv[t] = bv[(size_t)t * 512 + c];
#pragma unroll
            for (int so = 0; so < 4; ++so) {
                float bsum = attv[so * 4 + 0] * bvv[0] + attv[so * 4 + 1] * bvv[1]
                           + attv[so * 4 + 2] * bvv[2] + attv[so * 4 + 3] * bvv[3];
#pragma unroll
                for (int nf = 0; nf < 2; ++nf) {
                    int p = p0 + wc2 * 32 + nf * 16 + li;
                    size_t off = ((size_t)(b * 4 + so) * C_ + c) * HW_ + p;
                    out[off] = gm * (mst[so][mf][nf][r] + bsum) + x[off];
                }
            }
        }
    }
}

// ---------------------------------------------------------------------------
// gram5: all 24 reductions per (b, D/16-slice); Q/K read once. Deterministic.
// ---------------------------------------------------------------------------
__global__ __launch_bounds__(256) void gram5(
    const ushort_t* __restrict__ Q, const ushort_t* __restrict__ K,
    float* __restrict__ g4) {

    const int ch = blockIdx.x;       // 0..15
    const int b  = blockIdx.y;       // 0..7
    const size_t base = (size_t)ch * (D_ / 16);

    const uint4* qv[4];
    const uint4* kv[4];
#pragma unroll
    for (int s = 0; s < 4; ++s) {
        qv[s] = reinterpret_cast<const uint4*>(Q + (size_t)(b * 4 + s) * D_ + base);
        kv[s] = reinterpret_cast<const uint4*>(K + (size_t)(b * 4 + s) * D_ + base);
    }

    float accr[24];
#pragma unroll
    for (int e = 0; e < 24; ++e) accr[e] = 0.f;

    const int n8 = (int)(D_ / 16 / 8);
    for (int i = threadIdx.x; i < n8; i += 256) {
        uint4 qa[4], ka[4];
#pragma unroll
        for (int s = 0; s < 4; ++s) { qa[s] = qv[s][i]; ka[s] = kv[s][i]; }
#pragma unroll
        for (int s = 0; s < 4; ++s) {
#pragma unroll
            for (int u = 0; u < 4; ++u) accr[s * 4 + u] += dot8(qa[s], ka[u]);
            accr[16 + s] += dot8(qa[s], qa[s]);
            accr[20 + s] += dot8(ka[s], ka[s]);
        }
    }

    __shared__ float red[4][24];
    const int lane = threadIdx.x & 63, wid = threadIdx.x >> 6;
#pragma unroll
    for (int e = 0; e < 24; ++e) {
        float v = accr[e];
#pragma unroll
        for (int o = 32; o > 0; o >>= 1) v += __shfl_down(v, o);
        if (lane == 0) red[wid][e] = v;
    }
    __syncthreads();
    if (threadIdx.x < 24) {
        float t = red[0][threadIdx.x] + red[1][threadIdx.x]
                + red[2][threadIdx.x] + red[3][threadIdx.x];
        g4[((size_t)b * 24 + threadIdx.x) * 16 + ch] = t;
    }
}

__global__ void att_k5(const float* __restrict__ g4, float* __restrict__ att) {
    const int b = threadIdx.x;
    if (b >= B_) return;
    float e_[24];
#pragma unroll
    for (int e = 0; e < 24; ++e) {
        const float* p = g4 + ((size_t)b * 24 + e) * 16;
        float t = 0.f;
#pragma unroll
        for (int ch = 0; ch < 16; ++ch) t += p[ch];
        e_[e] = t;
    }
    float nq[4], nk[4];
#pragma unroll
    for (int s = 0; s < 4; ++s) {
        nq[s] = sqrtf(e_[16 + s]) + EPS_F;
        nk[s] = sqrtf(e_[20 + s]) + EPS_F;
    }
#pragma unroll
    for (int s = 0; s < 4; ++s) {
        float e[4], m = -1e30f;
#pragma unroll
        for (int t = 0; t < 4; ++t) {
            e[t] = e_[s * 4 + t] / (nq[s] * nk[t]);
            m = fmaxf(m, e[t]);
        }
        float sum = 0.f;
#pragma unroll
        for (int t = 0; t < 4; ++t) { e[t] = expf(e[t] - m); sum += e[t]; }
#pragma unroll
        for (int t = 0; t < 4; ++t) att[(size_t)(b * 4 + s) * 4 + t] = e[t] / sum;
    }
}

extern "C" void kernel_launch(void* const* d_in, const int* in_sizes, int n_in,
                              void* d_out, int out_size, void* d_ws, size_t ws_size,
                              hipStream_t stream) {
    const float* x     = (const float*)d_in[0];
    const float* wq    = (const float*)d_in[1];
    const float* bq    = (const float*)d_in[2];
    const float* wk    = (const float*)d_in[3];
    const float* bk    = (const float*)d_in[4];
    const float* wv    = (const float*)d_in[5];
    const float* bv    = (const float*)d_in[6];
    const float* gamma = (const float*)d_in[7];
    float* out = (float*)d_out;

    char* ws = (char*)d_ws;
    const size_t qk_elems = (size_t)B_ * S_ * Cq_ * HW_;       // 16,777,216
    ushort_t* Qb      = (ushort_t*)ws;                          // 33.55 MB
    ushort_t* Kb      = Qb + qk_elems;                          // 33.55 MB
    ushort_t* Wqk_pre = Kb + qk_elems;                          // 1.05 MB
    ushort_t* Wvb_pre = Wqk_pre + (size_t)4 * 8 * 256 * 64;     // 4.19 MB
    float*    g4      = (float*)(Wvb_pre + (size_t)4 * 2 * 8 * 256 * 64);
    float*    att     = g4 + 8 * 24 * 16;
    ushort_t* xbfT    = (ushort_t*)(att + 128);                 // 134.2 MB

    prep3<<<768, 256, 0, stream>>>(wq, wk, wv, Wqk_pre, Wvb_pre, g4);
    qk8<<<8192, 512, 0, stream>>>(Wqk_pre, x, bq, bk, Qb, Kb, xbfT);
    gram5<<<dim3(16, 8), 256, 0, stream>>>(Qb, Kb, g4);
    att_k5<<<1, 64, 0, stream>>>(g4, att);
    vblend8<<<4096, 256, 0, stream>>>(Wvb_pre, xbfT, x, bv, att, gamma, out);
}